// Round 4
// baseline (485.469 us; speedup 1.0000x reference)
//
#include <hip/hip_runtime.h>
#include <hip/hip_bf16.h>

typedef __attribute__((ext_vector_type(8))) short bf16x8;
typedef __attribute__((ext_vector_type(4))) float f32x4;

#define NB 8
#define NC 256
#define ND 32
#define NN 16384
#define TILE_P 32

#define MFMA16(a, b, c) __builtin_amdgcn_mfma_f32_16x16x32_bf16((a), (b), (c), 0, 0, 0)

__device__ __forceinline__ float u2f(unsigned short u) {
  union { unsigned int i; float f; } v; v.i = ((unsigned int)u) << 16; return v.f;
}
__device__ __forceinline__ unsigned short f2u(float f) {
  union { float f; unsigned int i; } v; v.f = f;
  unsigned int x = v.i;
  return (unsigned short)((x + 0x7fffu + ((x >> 16) & 1u)) >> 16);  // RNE
}
__device__ __forceinline__ float ldg(const void* p, size_t i, int isbf) {
  return isbf ? u2f(((const unsigned short*)p)[i]) : ((const float*)p)[i];
}
// swizzled LDS addressing: row p (512B rows), byte col colb, 16B-block XOR swizzle.
// XOR touches only bits 4-6, so any aligned <=16B access stays contiguous.
__device__ __forceinline__ char* lds_at(char* base, int p, int colb) {
  return base + (p << 9) + (colb ^ ((p & 7) << 4));
}

// ---------------- dtype detect ----------------
__global__ __launch_bounds__(256) void detect_kernel(const void* __restrict__ x,
                                                     int* __restrict__ flag) {
  __shared__ int red[4];
  const unsigned int* w = (const unsigned int*)x;
  int cnt = 0;
  for (int i = threadIdx.x; i < 4096; i += 256) {
    unsigned int e = (w[i] >> 7) & 0xFFu;
    cnt += (e >= 100u && e <= 135u) ? 1 : 0;
  }
  for (int off = 32; off; off >>= 1) cnt += __shfl_xor(cnt, off, 64);
  if ((threadIdx.x & 63) == 0) red[threadIdx.x >> 6] = cnt;
  __syncthreads();
  if (threadIdx.x == 0)
    flag[0] = (red[0] + red[1] + red[2] + red[3] > 2048) ? 1 : 0;
}

// ---------------- prep: pack Wq/Wp/Wkv into per-lane MFMA A-fragment layout ----------------
// slot = (kt*NMB + mb)*64 + lane ; lane holds W[o = mb*16+(lane&15)][k = kt*32+8*(lane>>4)+e]
__global__ __launch_bounds__(256) void prep_weights(
    const void* __restrict__ wq, const void* __restrict__ wp,
    const void* __restrict__ wkv, const int* __restrict__ flag,
    unsigned short* __restrict__ WqPh, unsigned short* __restrict__ WqPl,
    unsigned short* __restrict__ WpPh, unsigned short* __restrict__ WpPl,
    unsigned short* __restrict__ WkPh, unsigned short* __restrict__ WkPl) {
  int isbf = flag[0];
  int idx = blockIdx.x * 256 + threadIdx.x;  // 17408 total
  const void* w;
  unsigned short *Ph, *Pl;
  int slot, o, k0;
  if (idx < 16384) {
    int mat = idx >> 13;
    slot = idx & 8191;
    int lane = slot & 63;
    int mbkt = slot >> 6;
    int mb = mbkt & 15, kt = mbkt >> 4;
    o = mb * 16 + (lane & 15);
    k0 = kt * 32 + (lane >> 4) * 8;
    w = mat ? wp : wq;
    Ph = mat ? WpPh : WqPh;
    Pl = mat ? WpPl : WqPl;
  } else {
    slot = idx - 16384;  // [0, 1024)
    int lane = slot & 63;
    int grp = slot >> 6;
    int mb = grp & 1, kt = grp >> 1;
    o = mb * 16 + (lane & 15);
    k0 = kt * 32 + (lane >> 4) * 8;
    w = wkv;
    Ph = WkPh;
    Pl = WkPl;
  }
  unsigned short h[8], lo[8];
#pragma unroll
  for (int e = 0; e < 8; e++) {
    float v = ldg(w, (size_t)o * NC + k0 + e, isbf);
    unsigned short hh = f2u(v);
    h[e] = hh;
    lo[e] = isbf ? (unsigned short)0 : f2u(v - u2f(hh));
  }
  uint4 ph, pl;
  ph.x = h[0] | ((unsigned)h[1] << 16);
  ph.y = h[2] | ((unsigned)h[3] << 16);
  ph.z = h[4] | ((unsigned)h[5] << 16);
  ph.w = h[6] | ((unsigned)h[7] << 16);
  pl.x = lo[0] | ((unsigned)lo[1] << 16);
  pl.y = lo[2] | ((unsigned)lo[3] << 16);
  pl.z = lo[4] | ((unsigned)lo[5] << 16);
  pl.w = lo[6] | ((unsigned)lo[7] << 16);
  *(uint4*)(Ph + (size_t)slot * 8) = ph;
  *(uint4*)(Pl + (size_t)slot * 8) = pl;
}

// ---------------- kv = affine(Wkv @ X) via MFMA -> Kh/Kl bf16 hi/lo ----------------
// 64 px/block; fp32 mode stages K in two 128-ch halves (32K pool -> 4 blocks/CU).
template <int ISBF>
__global__ __launch_bounds__(256, 4) void kv_mfma(
    const void* __restrict__ x, const unsigned short* __restrict__ WkPh,
    const unsigned short* __restrict__ WkPl, const void* __restrict__ kv_scale,
    const void* __restrict__ kv_bias, const int* __restrict__ flag,
    unsigned short* __restrict__ Kh, unsigned short* __restrict__ Kl) {
  __shared__ __align__(16) char pool[32768];
  if (flag[0] != ISBF) return;
  const int tid = threadIdx.x;
  const int b = blockIdx.x >> 8;
  const int n0 = (blockIdx.x & 255) * 64;
  const int w = tid >> 6, l = tid & 63, g = l >> 4, cc = l & 15;
  const f32x4 zero4 = {0.f, 0.f, 0.f, 0.f};
  f32x4 acc[2] = {zero4, zero4};
  const bf16x8* Ah = (const bf16x8*)WkPh;
  const bf16x8* Al = (const bf16x8*)WkPl;

  if constexpr (ISBF) {
    // stage full 256ch x 64px, hi only; rows = px (512B), cols = ch*2
    const int pq = (tid & 15) * 4;
    const int c0 = (tid >> 4) * 16;
    const unsigned short* xp =
        (const unsigned short*)x + ((size_t)(b * NC + c0)) * NN + n0 + pq;
    unsigned short hi[16][4];
#pragma unroll
    for (int i = 0; i < 16; i++) {
      ushort4 r = *(const ushort4*)(xp + (size_t)i * NN);
      hi[i][0] = r.x; hi[i][1] = r.y; hi[i][2] = r.z; hi[i][3] = r.w;
    }
#pragma unroll
    for (int j = 0; j < 4; j++) {
      int p = pq + j;
#pragma unroll
      for (int half = 0; half < 2; half++) {
        uint4 wv;
        wv.x = hi[8*half+0][j] | ((unsigned)hi[8*half+1][j] << 16);
        wv.y = hi[8*half+2][j] | ((unsigned)hi[8*half+3][j] << 16);
        wv.z = hi[8*half+4][j] | ((unsigned)hi[8*half+5][j] << 16);
        wv.w = hi[8*half+6][j] | ((unsigned)hi[8*half+7][j] << 16);
        *(uint4*)lds_at(pool, p, c0 * 2 + half * 16) = wv;
      }
    }
    __syncthreads();
#pragma unroll
    for (int kt = 0; kt < 8; kt++) {
      bf16x8 xb = *(const bf16x8*)lds_at(pool, 16 * w + cc, kt * 64 + 16 * g);
      bf16x8 a0 = Ah[(kt * 2 + 0) * 64 + l];
      bf16x8 a1 = Ah[(kt * 2 + 1) * 64 + l];
      acc[0] = MFMA16(a0, xb, acc[0]);
      acc[1] = MFMA16(a1, xb, acc[1]);
    }
  } else {
#pragma unroll
    for (int kh = 0; kh < 2; kh++) {
      // stage 128ch x 64px hi+lo: hi at cols [0,256), lo at [256,512)
      const int pq = (tid & 15) * 4;
      const int c0l = (tid >> 4) * 8;
      const float* xp =
          (const float*)x + ((size_t)(b * NC + kh * 128 + c0l)) * NN + n0 + pq;
      unsigned short hi[8][4], lo[8][4];
#pragma unroll
      for (int i = 0; i < 8; i++) {
        float4 v = *(const float4*)(xp + (size_t)i * NN);
        float vv[4] = {v.x, v.y, v.z, v.w};
#pragma unroll
        for (int j = 0; j < 4; j++) {
          unsigned short hh = f2u(vv[j]);
          hi[i][j] = hh;
          lo[i][j] = f2u(vv[j] - u2f(hh));
        }
      }
      if (kh) __syncthreads();  // all waves done reading half 0
#pragma unroll
      for (int j = 0; j < 4; j++) {
        int p = pq + j;
        uint4 wv, wl2;
        wv.x = hi[0][j] | ((unsigned)hi[1][j] << 16);
        wv.y = hi[2][j] | ((unsigned)hi[3][j] << 16);
        wv.z = hi[4][j] | ((unsigned)hi[5][j] << 16);
        wv.w = hi[6][j] | ((unsigned)hi[7][j] << 16);
        wl2.x = lo[0][j] | ((unsigned)lo[1][j] << 16);
        wl2.y = lo[2][j] | ((unsigned)lo[3][j] << 16);
        wl2.z = lo[4][j] | ((unsigned)lo[5][j] << 16);
        wl2.w = lo[6][j] | ((unsigned)lo[7][j] << 16);
        *(uint4*)lds_at(pool, p, c0l * 2) = wv;
        *(uint4*)lds_at(pool, p, c0l * 2 + 256) = wl2;
      }
      __syncthreads();
#pragma unroll
      for (int kt = 0; kt < 4; kt++) {
        int ktg = kh * 4 + kt;
        bf16x8 xh = *(const bf16x8*)lds_at(pool, 16 * w + cc, kt * 64 + 16 * g);
        bf16x8 xl = *(const bf16x8*)lds_at(pool, 16 * w + cc, kt * 64 + 16 * g + 256);
        bf16x8 a0 = Ah[(ktg * 2 + 0) * 64 + l];
        bf16x8 a1 = Ah[(ktg * 2 + 1) * 64 + l];
        bf16x8 l0 = Al[(ktg * 2 + 0) * 64 + l];
        bf16x8 l1 = Al[(ktg * 2 + 1) * 64 + l];
        acc[0] = MFMA16(a0, xh, acc[0]);
        acc[0] = MFMA16(a0, xl, acc[0]);
        acc[0] = MFMA16(l0, xh, acc[0]);
        acc[1] = MFMA16(a1, xh, acc[1]);
        acc[1] = MFMA16(a1, xl, acc[1]);
        acc[1] = MFMA16(l1, xh, acc[1]);
      }
    }
  }

  const int n = n0 + 16 * w + cc;
#pragma unroll
  for (int mi = 0; mi < 2; mi++) {
#pragma unroll
    for (int rr = 0; rr < 4; rr++) {
      int d = mi * 16 + 4 * g + rr;
      float v = acc[mi][rr] * ldg(kv_scale, d, ISBF) + ldg(kv_bias, d, ISBF);
      unsigned short h16 = f2u(v);
      unsigned short l16 = f2u(v - u2f(h16));
      size_t off = ((size_t)(b * ND + d)) * NN + n;
      Kh[off] = h16;
      Kl[off] = l16;
    }
  }
}

// ---------------- ctx partials: S[d][e] = sum_n E[d][n]*kv[e][n], Z[d]=sum E ----------------
// No LDS, no atomics. E = exp(kh+kl) recomputed in-register (m == 0: |kv| bounded).
// 128 blocks x 4 waves; each wave owns a 256-px range and the full 32x32 S tile.
__global__ __launch_bounds__(256) void ctx_mfma(const unsigned short* __restrict__ Kh,
                                                const unsigned short* __restrict__ Kl,
                                                float* __restrict__ Spart,
                                                float* __restrict__ Zpart) {
  const int tid = threadIdx.x;
  const int bid = blockIdx.x;
  const int b = bid >> 4;
  const int w = tid >> 6, l = tid & 63, g = l >> 4, cc = l & 15;
  const int nbase = (bid & 15) * 1024 + w * 256;
  const f32x4 zero4 = {0.f, 0.f, 0.f, 0.f};
  f32x4 s00 = zero4, s01 = zero4, s10 = zero4, s11 = zero4;
  float z0 = 0.f, z1 = 0.f;
  const size_t row0 = ((size_t)(b * ND) + cc) * NN;
  const size_t row1 = ((size_t)(b * ND) + 16 + cc) * NN;
#pragma unroll
  for (int kt = 0; kt < 8; kt++) {
    int nn = nbase + kt * 32 + 8 * g;
    bf16x8 kh0 = *(const bf16x8*)(Kh + row0 + nn);
    bf16x8 kl0 = *(const bf16x8*)(Kl + row0 + nn);
    bf16x8 kh1 = *(const bf16x8*)(Kh + row1 + nn);
    bf16x8 kl1 = *(const bf16x8*)(Kl + row1 + nn);
    bf16x8 eh0, el0, eh1, el1;
#pragma unroll
    for (int e = 0; e < 8; e++) {
      float v0 = u2f((unsigned short)kh0[e]) + u2f((unsigned short)kl0[e]);
      float ev0 = __expf(v0);
      z0 += ev0;
      unsigned short h0 = f2u(ev0);
      eh0[e] = (short)h0;
      el0[e] = (short)f2u(ev0 - u2f(h0));
      float v1 = u2f((unsigned short)kh1[e]) + u2f((unsigned short)kl1[e]);
      float ev1 = __expf(v1);
      z1 += ev1;
      unsigned short h1 = f2u(ev1);
      eh1[e] = (short)h1;
      el1[e] = (short)f2u(ev1 - u2f(h1));
    }
    s00 = MFMA16(eh0, kh0, s00); s00 = MFMA16(eh0, kl0, s00); s00 = MFMA16(el0, kh0, s00);
    s01 = MFMA16(eh0, kh1, s01); s01 = MFMA16(eh0, kl1, s01); s01 = MFMA16(el0, kh1, s01);
    s10 = MFMA16(eh1, kh0, s10); s10 = MFMA16(eh1, kl0, s10); s10 = MFMA16(el1, kh0, s10);
    s11 = MFMA16(eh1, kh1, s11); s11 = MFMA16(eh1, kl1, s11); s11 = MFMA16(el1, kh1, s11);
  }
  // Z: reduce over g (lanes differing in bits 4,5)
  z0 += __shfl_xor(z0, 16, 64); z0 += __shfl_xor(z0, 32, 64);
  z1 += __shfl_xor(z1, 16, 64); z1 += __shfl_xor(z1, 32, 64);
  if (l < 16) {
    Zpart[((size_t)bid * 4 + w) * ND + cc] = z0;
    Zpart[((size_t)bid * 4 + w) * ND + 16 + cc] = z1;
  }
  float* sp = Spart + ((size_t)bid * 4 + w) * 1024;
#pragma unroll
  for (int rr = 0; rr < 4; rr++) {
    int r0 = (4 * g + rr) * 32;
    int r1 = (16 + 4 * g + rr) * 32;
    sp[r0 + cc] = s00[rr];
    sp[r0 + 16 + cc] = s01[rr];
    sp[r1 + cc] = s10[rr];
    sp[r1 + 16 + cc] = s11[rr];
  }
}

// ---------------- reduce partials + divide -> ctx[b][d][e] ----------------
__global__ __launch_bounds__(256) void ctx_redfin(const float* __restrict__ Spart,
                                                  const float* __restrict__ Zpart,
                                                  float* __restrict__ ctx) {
  int i = blockIdx.x * 256 + threadIdx.x;  // 8192
  int b = i >> 10, cell = i & 1023, d = cell >> 5;
  float s = 0.f, z = 0.f;
  for (int j = 0; j < 64; j++) {
    s += Spart[(size_t)(b * 64 + j) * 1024 + cell];
    z += Zpart[(size_t)(b * 64 + j) * ND + d];
  }
  ctx[i] = s / z;
}

// ---------------- fused: q GEMM -> softmax(D) -> ctx matvec -> relu -> out GEMM ----------------
// fp32: split-K X staging (two 128-ch halves, hi+lo packed in one 16K region);
// Y stored hi-only; GEMM1 3-term, ctx 3-term, GEMM2 2-term. Pool 50176+4K -> 3 blocks/CU.
template <int ISBF>
__global__ __launch_bounds__(256, 3) void fused_main(
    const void* __restrict__ x,
    const unsigned short* __restrict__ WqPh, const unsigned short* __restrict__ WqPl,
    const unsigned short* __restrict__ WpPh, const unsigned short* __restrict__ WpPl,
    const void* __restrict__ q_scale, const void* __restrict__ q_bias,
    const void* __restrict__ p_scale, const void* __restrict__ p_bias,
    const float* __restrict__ ctx, const int* __restrict__ flag,
    void* __restrict__ out) {
  constexpr int SMH_O = 16384;
  constexpr int SML_O = 32768;
  constexpr int OT_O = 16384;               // overlays SM after ctx GEMM
  constexpr int OT_STR = ISBF ? 88 : 132;
  constexpr int POOL = ISBF ? 49152 : 50176;
  __shared__ __align__(16) char pool[POOL];
  __shared__ float qs_l[NC], qb_l[NC], ps_l[NC], pb_l[NC];
  if (flag[0] != ISBF) return;
  const int tid = threadIdx.x;
  const int b = blockIdx.x >> 9;
  const int n0 = (blockIdx.x & 511) * TILE_P;
  const int w = tid >> 6;
  const int l = tid & 63;
  const int g = l >> 4;
  const int cc = l & 15;
  const f32x4 zero4 = {0.f, 0.f, 0.f, 0.f};

  qs_l[tid] = ldg(q_scale, tid, ISBF);
  qb_l[tid] = ldg(q_bias, tid, ISBF);
  ps_l[tid] = ldg(p_scale, tid, ISBF);
  pb_l[tid] = ldg(p_bias, tid, ISBF);

  // ctx A-fragments: A[m=e][k=d] = ctx[d][e], hi/lo
  bf16x8 cAh[2], cAl[2];
  {
    const float* cb = ctx + (size_t)b * ND * ND;
#pragma unroll
    for (int mp = 0; mp < 2; mp++) {
      bf16x8 ah, al;
#pragma unroll
      for (int el = 0; el < 8; el++) {
        float v = cb[(8 * g + el) * ND + 16 * mp + cc];
        unsigned short hh = f2u(v);
        ah[el] = (short)hh;
        al[el] = (short)f2u(v - u2f(hh));
      }
      cAh[mp] = ah; cAl[mp] = al;
    }
  }

  f32x4 acc[4][2];
#pragma unroll
  for (int mi = 0; mi < 4; mi++) { acc[mi][0] = zero4; acc[mi][1] = zero4; }

  if constexpr (ISBF) {
    // stage full X tile (hi only), then GEMM1 1-term
    {
      const int c0 = (tid >> 3) * 8;
      const int pq = (tid & 7) * 4;
      const unsigned short* xp =
          (const unsigned short*)x + ((size_t)(b * NC + c0)) * NN + n0 + pq;
      unsigned short hi[8][4];
#pragma unroll
      for (int i = 0; i < 8; i++) {
        ushort4 r = *(const ushort4*)(xp + (size_t)i * NN);
        hi[i][0] = r.x; hi[i][1] = r.y; hi[i][2] = r.z; hi[i][3] = r.w;
      }
#pragma unroll
      for (int j = 0; j < 4; j++) {
        int p = pq + j;
        uint4 wv;
        wv.x = hi[0][j] | ((unsigned)hi[1][j] << 16);
        wv.y = hi[2][j] | ((unsigned)hi[3][j] << 16);
        wv.z = hi[4][j] | ((unsigned)hi[5][j] << 16);
        wv.w = hi[6][j] | ((unsigned)hi[7][j] << 16);
        *(uint4*)lds_at(pool, p, c0 * 2) = wv;
      }
    }
    __syncthreads();
    const bf16x8* Aq = (const bf16x8*)WqPh;
#pragma unroll
    for (int kt = 0; kt < 8; kt++) {
      bf16x8 xb0 = *(const bf16x8*)lds_at(pool, cc, kt * 64 + 16 * g);
      bf16x8 xb1 = *(const bf16x8*)lds_at(pool, 16 + cc, kt * 64 + 16 * g);
#pragma unroll
      for (int mi = 0; mi < 4; mi++) {
        bf16x8 av = Aq[(kt * 16 + w * 4 + mi) * 64 + l];
        acc[mi][0] = MFMA16(av, xb0, acc[mi][0]);
        acc[mi][1] = MFMA16(av, xb1, acc[mi][1]);
      }
    }
  } else {
    // two K-halves: stage 128ch hi+lo into 16K region, GEMM1 3-term
    const bf16x8* Aq = (const bf16x8*)WqPh;
    const bf16x8* Aql = (const bf16x8*)WqPl;
#pragma unroll
    for (int kh = 0; kh < 2; kh++) {
      const int c0l = (tid >> 3) * 4;
      const int pq = (tid & 7) * 4;
      const float* xp =
          (const float*)x + ((size_t)(b * NC + kh * 128 + c0l)) * NN + n0 + pq;
      unsigned short hi[4][4], lo[4][4];
#pragma unroll
      for (int i = 0; i < 4; i++) {
        float4 v = *(const float4*)(xp + (size_t)i * NN);
        float vv[4] = {v.x, v.y, v.z, v.w};
#pragma unroll
        for (int j = 0; j < 4; j++) {
          unsigned short hh = f2u(vv[j]);
          hi[i][j] = hh;
          lo[i][j] = f2u(vv[j] - u2f(hh));
        }
      }
      if (kh) __syncthreads();  // all waves done reading half 0
#pragma unroll
      for (int j = 0; j < 4; j++) {
        int p = pq + j;
        uint2 wv, wl2;
        wv.x = hi[0][j] | ((unsigned)hi[1][j] << 16);
        wv.y = hi[2][j] | ((unsigned)hi[3][j] << 16);
        wl2.x = lo[0][j] | ((unsigned)lo[1][j] << 16);
        wl2.y = lo[2][j] | ((unsigned)lo[3][j] << 16);
        *(uint2*)lds_at(pool, p, c0l * 2) = wv;
        *(uint2*)lds_at(pool, p, c0l * 2 + 256) = wl2;
      }
      __syncthreads();
#pragma unroll
      for (int kt = 0; kt < 4; kt++) {
        int ktg = kh * 4 + kt;
        bf16x8 xb0 = *(const bf16x8*)lds_at(pool, cc, kt * 64 + 16 * g);
        bf16x8 xl0 = *(const bf16x8*)lds_at(pool, cc, kt * 64 + 16 * g + 256);
        bf16x8 xb1 = *(const bf16x8*)lds_at(pool, 16 + cc, kt * 64 + 16 * g);
        bf16x8 xl1 = *(const bf16x8*)lds_at(pool, 16 + cc, kt * 64 + 16 * g + 256);
#pragma unroll
        for (int mi = 0; mi < 4; mi++) {
          bf16x8 av = Aq[(ktg * 16 + w * 4 + mi) * 64 + l];
          bf16x8 al2 = Aql[(ktg * 16 + w * 4 + mi) * 64 + l];
          acc[mi][0] = MFMA16(av, xb0, acc[mi][0]);
          acc[mi][0] = MFMA16(av, xl0, acc[mi][0]);
          acc[mi][0] = MFMA16(al2, xb0, acc[mi][0]);
          acc[mi][1] = MFMA16(av, xb1, acc[mi][1]);
          acc[mi][1] = MFMA16(av, xl1, acc[mi][1]);
          acc[mi][1] = MFMA16(al2, xb1, acc[mi][1]);
        }
      }
    }
  }

  // ---- softmax over D per (head,pixel); E hi/lo -> SM tiles ----
  float inv_s[2][2];
#pragma unroll
  for (int hp = 0; hp < 2; hp++) {
#pragma unroll
    for (int ni = 0; ni < 2; ni++) {
      float e8[8];
      float mx = -3.0e38f;
#pragma unroll
      for (int mi2 = 0; mi2 < 2; mi2++) {
#pragma unroll
        for (int r = 0; r < 4; r++) {
          int o = w * 64 + (2 * hp + mi2) * 16 + 4 * g + r;
          float v = acc[2 * hp + mi2][ni][r] * qs_l[o] + qb_l[o];
          e8[mi2 * 4 + r] = v;
          mx = fmaxf(mx, v);
        }
      }
      mx = fmaxf(mx, __shfl_xor(mx, 16, 64));
      mx = fmaxf(mx, __shfl_xor(mx, 32, 64));
      float s = 0.f;
#pragma unroll
      for (int i2 = 0; i2 < 8; i2++) { e8[i2] = __expf(e8[i2] - mx); s += e8[i2]; }
      s += __shfl_xor(s, 16, 64);
      s += __shfl_xor(s, 32, 64);
      inv_s[hp][ni] = 1.f / s;
      int p = ni * 16 + cc;
#pragma unroll
      for (int mi2 = 0; mi2 < 2; mi2++) {
        int colb = (w * 64 + (2 * hp + mi2) * 16 + 4 * g) * 2;
        unsigned short h[4], lo2[4];
#pragma unroll
        for (int r = 0; r < 4; r++) {
          float ev = e8[mi2 * 4 + r];
          unsigned short hh = f2u(ev);
          h[r] = hh;
          lo2[r] = f2u(ev - u2f(hh));
        }
        uint2 wh, wl2;
        wh.x = h[0] | ((unsigned)h[1] << 16);
        wh.y = h[2] | ((unsigned)h[3] << 16);
        wl2.x = lo2[0] | ((unsigned)lo2[1] << 16);
        wl2.y = lo2[2] | ((unsigned)lo2[3] << 16);
        *(uint2*)lds_at(pool + SMH_O, p, colb) = wh;
        *(uint2*)lds_at(pool + SML_O, p, colb) = wl2;
      }
    }
  }
  __syncthreads();  // (1) all X reads done; SM tiles complete

  // ---- ctx GEMM: att = ctx^T @ E (3-term), /s, relu -> YT (hi only) at pool[0,16K) ----
#pragma unroll
  for (int hp = 0; hp < 2; hp++) {
    f32x4 cacc[2][2];
#pragma unroll
    for (int mp = 0; mp < 2; mp++) { cacc[mp][0] = zero4; cacc[mp][1] = zero4; }
#pragma unroll
    for (int ni = 0; ni < 2; ni++) {
      int p = ni * 16 + cc;
      int colb = ((2 * w + hp) * 32 + 8 * g) * 2;
      bf16x8 bh = *(const bf16x8*)lds_at(pool + SMH_O, p, colb);
      bf16x8 bl = *(const bf16x8*)lds_at(pool + SML_O, p, colb);
#pragma unroll
      for (int mp = 0; mp < 2; mp++) {
        cacc[mp][ni] = MFMA16(cAh[mp], bh, cacc[mp][ni]);
        cacc[mp][ni] = MFMA16(cAh[mp], bl, cacc[mp][ni]);
        cacc[mp][ni] = MFMA16(cAl[mp], bh, cacc[mp][ni]);
      }
    }
#pragma unroll
    for (int mp = 0; mp < 2; mp++) {
#pragma unroll
      for (int ni = 0; ni < 2; ni++) {
        int p = ni * 16 + cc;
        float iv = inv_s[hp][ni];
        unsigned short h[4];
#pragma unroll
        for (int r = 0; r < 4; r++)
          h[r] = f2u(fmaxf(cacc[mp][ni][r] * iv, 0.f));
        int colb = ((2 * w + hp) * 32 + mp * 16 + 4 * g) * 2;
        uint2 wh;
        wh.x = h[0] | ((unsigned)h[1] << 16);
        wh.y = h[2] | ((unsigned)h[3] << 16);
        *(uint2*)lds_at(pool, p, colb) = wh;
      }
    }
  }
  __syncthreads();  // (2) YT complete; SM reads done

  // ---- GEMM2: out = Wp @ relu(att); fp32: (Wph+Wpl)*Yh, bf16: Wph*Yh ----
  f32x4 oacc[4][2];
#pragma unroll
  for (int mi = 0; mi < 4; mi++) { oacc[mi][0] = zero4; oacc[mi][1] = zero4; }
  {
    const bf16x8* Ap = (const bf16x8*)WpPh;
    const bf16x8* Apl = (const bf16x8*)WpPl;
#pragma unroll
    for (int kt = 0; kt < 8; kt++) {
      bf16x8 yh0 = *(const bf16x8*)lds_at(pool, cc, kt * 64 + 16 * g);
      bf16x8 yh1 = *(const bf16x8*)lds_at(pool, 16 + cc, kt * 64 + 16 * g);
#pragma unroll
      for (int mi = 0; mi < 4; mi++) {
        bf16x8 av = Ap[(kt * 16 + w * 4 + mi) * 64 + l];
        oacc[mi][0] = MFMA16(av, yh0, oacc[mi][0]);
        oacc[mi][1] = MFMA16(av, yh1, oacc[mi][1]);
      }
      if (!ISBF) {
#pragma unroll
        for (int mi = 0; mi < 4; mi++) {
          bf16x8 al2 = Apl[(kt * 16 + w * 4 + mi) * 64 + l];
          oacc[mi][0] = MFMA16(al2, yh0, oacc[mi][0]);
          oacc[mi][1] = MFMA16(al2, yh1, oacc[mi][1]);
        }
      }
    }
  }

  // ---- epilogue: affine -> OT (channel-major) -> coalesced global store ----
  {
    char* OT = pool + OT_O;
#pragma unroll
    for (int mi = 0; mi < 4; mi++) {
#pragma unroll
      for (int ni = 0; ni < 2; ni++) {
#pragma unroll
        for (int r = 0; r < 4; r++) {
          int o = w * 64 + mi * 16 + 4 * g + r;
          float v = oacc[mi][ni][r] * ps_l[o] + pb_l[o];
          int p = ni * 16 + cc;
          if (ISBF)
            *(unsigned short*)(OT + o * OT_STR + p * 2) = f2u(v);
          else
            *(float*)(OT + o * OT_STR + p * 4) = v;
        }
      }
    }
  }
  __syncthreads();  // (3) OT complete
  {
    char* OT = pool + OT_O;
    int o = tid;
    size_t gbase = ((size_t)(b * NC + o)) * NN + n0;
    if (ISBF) {
      unsigned short* po = (unsigned short*)out + gbase;
#pragma unroll
      for (int k = 0; k < 4; k++) {
        uint2 a = *(const uint2*)(OT + o * OT_STR + k * 16);
        uint2 b2 = *(const uint2*)(OT + o * OT_STR + k * 16 + 8);
        *(uint4*)(po + k * 8) = make_uint4(a.x, a.y, b2.x, b2.y);
      }
    } else {
      float* po = (float*)out + gbase;
#pragma unroll
      for (int k = 0; k < 8; k++) {
        float4 v;
        v.x = *(const float*)(OT + o * OT_STR + (k * 4 + 0) * 4);
        v.y = *(const float*)(OT + o * OT_STR + (k * 4 + 1) * 4);
        v.z = *(const float*)(OT + o * OT_STR + (k * 4 + 2) * 4);
        v.w = *(const float*)(OT + o * OT_STR + (k * 4 + 3) * 4);
        *(float4*)(po + k * 4) = v;
      }
    }
  }
}

extern "C" void kernel_launch(void* const* d_in, const int* in_sizes, int n_in,
                              void* d_out, int out_size, void* d_ws, size_t ws_size,
                              hipStream_t stream) {
  const void* input   = d_in[0];
  const void* wq      = d_in[1];
  const void* q_scale = d_in[2];
  const void* q_bias  = d_in[3];
  const void* wkv     = d_in[4];
  const void* kv_scale= d_in[5];
  const void* kv_bias = d_in[6];
  const void* wp      = d_in[7];
  const void* p_scale = d_in[8];
  const void* p_bias  = d_in[9];

  char* w = (char*)d_ws;
  int*  flag = (int*)w;      w += 256;
  unsigned short* Kh = (unsigned short*)w; w += (size_t)NB * ND * NN * 2;  // 8 MiB
  unsigned short* Kl = (unsigned short*)w; w += (size_t)NB * ND * NN * 2;  // 8 MiB
  float* Zpart = (float*)w;  w += (size_t)512 * ND * 4;                    // 64 KiB
  float* Spart = (float*)w;  w += (size_t)512 * 1024 * 4;                  // 2 MiB
  float* ctx  = (float*)w;   w += (size_t)NB * ND * ND * 4;                // 32 KiB
  unsigned short* WqPh = (unsigned short*)w; w += (size_t)NC * NC * 2;
  unsigned short* WqPl = (unsigned short*)w; w += (size_t)NC * NC * 2;
  unsigned short* WpPh = (unsigned short*)w; w += (size_t)NC * NC * 2;
  unsigned short* WpPl = (unsigned short*)w; w += (size_t)NC * NC * 2;
  unsigned short* WkPh = (unsigned short*)w; w += (size_t)ND * NC * 2;
  unsigned short* WkPl = (unsigned short*)w; w += (size_t)ND * NC * 2;

  detect_kernel<<<1, 256, 0, stream>>>(input, flag);
  prep_weights<<<68, 256, 0, stream>>>(wq, wp, wkv, flag, WqPh, WqPl, WpPh, WpPl,
                                       WkPh, WkPl);
  kv_mfma<1><<<2048, 256, 0, stream>>>(input, WkPh, WkPl, kv_scale, kv_bias, flag, Kh, Kl);
  kv_mfma<0><<<2048, 256, 0, stream>>>(input, WkPh, WkPl, kv_scale, kv_bias, flag, Kh, Kl);
  ctx_mfma<<<128, 256, 0, stream>>>(Kh, Kl, Spart, Zpart);
  ctx_redfin<<<32, 256, 0, stream>>>(Spart, Zpart, ctx);
  fused_main<1><<<4096, 256, 0, stream>>>(input, WqPh, WqPl, WpPh, WpPl,
                                          q_scale, q_bias, p_scale, p_bias,
                                          ctx, flag, (void*)d_out);
  fused_main<0><<<4096, 256, 0, stream>>>(input, WqPh, WqPl, WpPh, WpPl,
                                          q_scale, q_bias, p_scale, p_bias,
                                          ctx, flag, (void*)d_out);
}